// Round 5
// baseline (390.474 us; speedup 1.0000x reference)
//
#include <hip/hip_runtime.h>

#define N_NODES   1000000
#define N_EDGES   2000000
#define N_FEAT    11
#define HIDDEN    64
#define BATCH     128
#define N_CLASSES 19

#define NPB       1024                            // nodes per bucket (bucket = col>>10)
#define NBUCK     ((N_NODES + NPB - 1) / NPB)     // 977
#define EPB       8192                            // edges per partition block
#define PBLK      ((N_EDGES + EPB - 1) / EPB)     // 245
#define NSLOT     8                               // pool slots per 256-node chunk
#define NCHUNK    (NBUCK * 4)                     // 3908 chunks of 256 nodes

// ---- K1: per-block LDS histogram of targets by bucket -> global bucket counts
__global__ __launch_bounds__(256) void hist_kernel(const int* __restrict__ col,
                                                   int* __restrict__ bcnt) {
    __shared__ int lh[NPB];
    for (int i = threadIdx.x; i < NPB; i += 256) lh[i] = 0;
    __syncthreads();
    const int base = blockIdx.x * EPB;
#pragma unroll
    for (int i = 0; i < EPB / 256; ++i) {
        int e = base + i * 256 + threadIdx.x;
        if (e < N_EDGES) atomicAdd(&lh[col[e] >> 10], 1);
    }
    __syncthreads();
    for (int b = threadIdx.x; b < NBUCK; b += 256) {
        int v = lh[b];
        if (v) atomicAdd(&bcnt[b], v);
    }
}

// ---- K2: exclusive scan of bucket counts ----
__global__ __launch_bounds__(1024) void scan_kernel(const int* __restrict__ bcnt,
                                                    int* __restrict__ bstart,
                                                    int* __restrict__ cursor,
                                                    int* __restrict__ cstart) {
    __shared__ int sh[1024];
    const int t = threadIdx.x;
    int v = (t < NBUCK) ? bcnt[t] : 0;
    sh[t] = v;
    __syncthreads();
    for (int off = 1; off < 1024; off <<= 1) {
        int a = (t >= off) ? sh[t - off] : 0;
        __syncthreads();
        sh[t] += a;
        __syncthreads();
    }
    if (t < NBUCK) { int ex = sh[t] - v; bstart[t] = ex; cursor[t] = ex; }
    if (t == 1023) cstart[NCHUNK] = N_EDGES;
}

// ---- K3: multisplit scatter — one global atomic per (block,bucket) ----
__global__ __launch_bounds__(256) void part_kernel(const int* __restrict__ row,
                                                   const int* __restrict__ col,
                                                   int* __restrict__ cursor,
                                                   unsigned* __restrict__ part) {
    __shared__ int lh[NPB];
    const int t = threadIdx.x;
    for (int i = t; i < NPB; i += 256) lh[i] = 0;
    __syncthreads();
    const int base = blockIdx.x * EPB;
#pragma unroll
    for (int i = 0; i < EPB / 256; ++i) {
        int e = base + i * 256 + t;
        if (e < N_EDGES) atomicAdd(&lh[col[e] >> 10], 1);
    }
    __syncthreads();
    for (int b = t; b < NBUCK; b += 256) {
        int v = lh[b];
        lh[b] = v ? atomicAdd(&cursor[b], v) : 0;   // lh becomes running write pos
    }
    __syncthreads();
#pragma unroll
    for (int i = 0; i < EPB / 256; ++i) {
        int e = base + i * 256 + t;
        if (e < N_EDGES) {
            int c = col[e];
            int pos = atomicAdd(&lh[c >> 10], 1);   // LDS rank
            part[pos] = ((unsigned)row[e] << 10) | (unsigned)(c & (NPB - 1));
        }
    }
}

// ---- K4: per-bucket counting sort (packed kept) + dinv + cstart + xs (fused xpad)
__global__ __launch_bounds__(256) void sort2_kernel(const unsigned* __restrict__ part,
                                                    const int* __restrict__ bstart,
                                                    const int* __restrict__ bcnt,
                                                    const float* __restrict__ x,
                                                    unsigned* __restrict__ srcs2,
                                                    int* __restrict__ cstart,
                                                    float* __restrict__ dinv,
                                                    float* __restrict__ xs) {
    __shared__ int cnt[NPB];
    __shared__ int off[NPB];
    __shared__ int tsum[256];
    const int t = threadIdx.x, b = blockIdx.x;
    for (int i = t; i < NPB; i += 256) cnt[i] = 0;
    __syncthreads();
    const int s0 = bstart[b], e0 = s0 + bcnt[b];
    for (int j = s0 + t; j < e0; j += 256)
        atomicAdd(&cnt[part[j] & (NPB - 1)], 1);
    __syncthreads();
    // exclusive scan of 1024 counts
    const int i0 = t * 4;
    int c0 = cnt[i0], c1 = cnt[i0 + 1], c2 = cnt[i0 + 2], c3 = cnt[i0 + 3];
    int s = c0 + c1 + c2 + c3;
    tsum[t] = s;
    __syncthreads();
    for (int o = 1; o < 256; o <<= 1) {
        int a = (t >= o) ? tsum[t - o] : 0;
        __syncthreads();
        tsum[t] += a;
        __syncthreads();
    }
    int ex = tsum[t] - s;
    off[i0] = ex; off[i0 + 1] = ex + c0; off[i0 + 2] = ex + c0 + c1; off[i0 + 3] = ex + c0 + c1 + c2;
    __syncthreads();
    // chunk starts (4 per bucket), dinv, and fused xpad: xs[n] = dinv[n]*x[n] padded
    if (t < 4) cstart[b * 4 + t] = s0 + off[t * 256];
    for (int i = t; i < NPB; i += 256) {
        int n = b * NPB + i;
        if (n < N_NODES) {
            int d = cnt[i];
            float dv = d ? rsqrtf((float)d) : 0.0f;
            dinv[n] = dv;
            const float* xr = x + (size_t)n * N_FEAT;
            float4 A, B, C;
            A.x = dv * xr[0];  A.y = dv * xr[1];  A.z = dv * xr[2];  A.w = dv * xr[3];
            B.x = dv * xr[4];  B.y = dv * xr[5];  B.z = dv * xr[6];  B.w = dv * xr[7];
            C.x = dv * xr[8];  C.y = dv * xr[9];  C.z = dv * xr[10]; C.w = 0.0f;
            float4* o = (float4*)(xs + (size_t)n * 16);
            o[0] = A; o[1] = B; o[2] = C;
        }
    }
    __syncthreads();
    // scatter into node-sorted order, keep packed payload
    for (int j = s0 + t; j < e0; j += 256) {
        unsigned p = part[j];
        int cl = (int)(p & (NPB - 1));
        int pos = s0 + atomicAdd(&off[cl], 1);
        srcs2[pos] = p;
    }
}

// ---- K5: edge-parallel gather + transform/relu + hierarchical mean-pool ----
// one block per 256-node chunk; edges of the chunk are contiguous in srcs2.
__global__ __launch_bounds__(256) void gather_pool_kernel(
    const int* __restrict__ cstart, const unsigned* __restrict__ srcs2,
    const float* __restrict__ xs, const float* __restrict__ dinv,
    const int* __restrict__ batch, const float* __restrict__ Wc,
    const float* __restrict__ bc, float* __restrict__ pooled,
    float* __restrict__ countsf) {
    __shared__ float facc[256 * N_FEAT];    // 11 KB
    __shared__ float sdinv[256];
    __shared__ int   sbid[256];
    __shared__ float pbuf[NSLOT * HIDDEN];  // 2 KB
    __shared__ int   pcnt[NSLOT];
    const int t = threadIdx.x, lane = t & 63, w = t >> 6;
    const int blk  = blockIdx.x;
    const int base = blk * 256;             // first node of chunk
    const int coff = (blk & 3) * 256;       // chunk offset within its bucket

    for (int i = t; i < 256 * N_FEAT; i += 256) facc[i] = 0.0f;
    for (int i = t; i < NSLOT * HIDDEN; i += 256) pbuf[i] = 0.0f;
    if (t < NSLOT) pcnt[t] = 0;
    {
        int n = base + t;
        sdinv[t] = (n < N_NODES) ? dinv[n]  : 0.0f;
        sbid[t]  = (n < N_NODES) ? batch[n] : -1;
    }
    __syncthreads();

    // phase A: edge-parallel, uniform work, high MLP
    const int e_lo = cstart[blk], e_hi = cstart[blk + 1];
    for (int j = e_lo + t; j < e_hi; j += 256) {
        unsigned p = srcs2[j];
        int r  = (int)(p >> 10);
        int cl = (int)(p & (NPB - 1)) - coff;   // 0..255
        const float4* xr = (const float4*)(xs + (size_t)r * 16);
        float4 A = xr[0], B = xr[1], C = xr[2]; // one 64B line, prescaled by dinv[r]
        float* f = &facc[cl * N_FEAT];
        atomicAdd(&f[0], A.x);  atomicAdd(&f[1], A.y);  atomicAdd(&f[2], A.z);
        atomicAdd(&f[3], A.w);  atomicAdd(&f[4], B.x);  atomicAdd(&f[5], B.y);
        atomicAdd(&f[6], B.z);  atomicAdd(&f[7], B.w);  atomicAdd(&f[8], C.x);
        atomicAdd(&f[9], C.y);  atomicAdd(&f[10], C.z);
    }
    __syncthreads();

    // phase B: wave w owns nodes [w*64, w*64+64) of the chunk; lane = channel
    float wk[N_FEAT];
#pragma unroll
    for (int k = 0; k < N_FEAT; ++k) wk[k] = Wc[k * HIDDEN + lane];
    const float bias = bc[lane];
    const int bid0 = sbid[0];
    int cur = -1; float accp = 0.0f; int cntp = 0;
    for (int i = w * 64; i < w * 64 + 64; ++i) {
        int bid = sbid[i];
        if (bid < 0) break;                 // past N_NODES
        if (bid != cur) {
            if (cur >= 0) {
                int slot = cur - bid0;
                if (slot >= 0 && slot < NSLOT) {
                    atomicAdd(&pbuf[slot * HIDDEN + lane], accp);
                    if (lane == 0) atomicAdd(&pcnt[slot], cntp);
                } else {
                    atomicAdd(&pooled[(size_t)cur * HIDDEN + lane], accp);
                    if (lane == 0) atomicAdd(&countsf[cur], (float)cntp);
                }
            }
            cur = bid; accp = 0.0f; cntp = 0;
        }
        float s = 0.0f;
#pragma unroll
        for (int k = 0; k < N_FEAT; ++k)
            s = fmaf(wk[k], facc[i * N_FEAT + k], s);   // LDS broadcast
        accp += fmaxf(fmaf(sdinv[i], s, bias), 0.0f);
        ++cntp;
    }
    if (cur >= 0) {
        int slot = cur - bid0;
        if (slot >= 0 && slot < NSLOT) {
            atomicAdd(&pbuf[slot * HIDDEN + lane], accp);
            if (lane == 0) atomicAdd(&pcnt[slot], cntp);
        } else {
            atomicAdd(&pooled[(size_t)cur * HIDDEN + lane], accp);
            if (lane == 0) atomicAdd(&countsf[cur], (float)cntp);
        }
    }
    __syncthreads();
    for (int s = w; s < NSLOT; s += 4) {
        int c = pcnt[s];
        if (c > 0) {
            atomicAdd(&pooled[(size_t)(bid0 + s) * HIDDEN + lane], pbuf[s * HIDDEN + lane]);
            if (lane == 0) atomicAdd(&countsf[bid0 + s], (float)c);
        }
    }
}

// ---- K6: out = (pooled/cnt) @ W_lin + b_lin ----
__global__ void final_kernel(const float* __restrict__ pooled, const float* __restrict__ counts,
                             const float* __restrict__ Wl, const float* __restrict__ bl,
                             float* __restrict__ out) {
    int i = blockIdx.x * blockDim.x + threadIdx.x;
    if (i >= BATCH * N_CLASSES) return;
    int b = i / N_CLASSES;
    int c = i - b * N_CLASSES;
    float inv = 1.0f / fmaxf(counts[b], 1.0f);
    float s = bl[c];
#pragma unroll 8
    for (int h = 0; h < HIDDEN; ++h)
        s = fmaf(pooled[b * HIDDEN + h] * inv, Wl[h * N_CLASSES + c], s);
    out[i] = s;
}

extern "C" void kernel_launch(void* const* d_in, const int* in_sizes, int n_in,
                              void* d_out, int out_size, void* d_ws, size_t ws_size,
                              hipStream_t stream) {
    // inputs: x, edge_index, y(unused), batch, W_conv, b_conv, W_lin, b_lin
    const float* x     = (const float*)d_in[0];
    const int*   ei    = (const int*)d_in[1];   // [2, E] int32
    const int*   batch = (const int*)d_in[3];
    const float* Wc    = (const float*)d_in[4];
    const float* bc    = (const float*)d_in[5];
    const float* Wl    = (const float*)d_in[6];
    const float* bl    = (const float*)d_in[7];
    float*       out   = (float*)d_out;

    // ws: xs[16M f] | bcnt[1024] pooled[8192] countsf[128] (zeroed) |
    //     bstart[1024] cursor[1024] | dinv[1M] | part[2M] | srcs2[2M] | cstart[NCHUNK+4]
    float*    xs      = (float*)d_ws;
    int*      bcnt    = (int*)(xs + (size_t)N_NODES * 16);
    float*    pooled  = (float*)(bcnt + 1024);
    float*    countsf = pooled + BATCH * HIDDEN;
    int*      bstart  = (int*)(countsf + BATCH);
    int*      cursor  = bstart + 1024;
    float*    dinv    = (float*)(cursor + 1024);
    unsigned* part    = (unsigned*)(dinv + N_NODES);
    unsigned* srcs2   = part + N_EDGES;
    int*      cstart  = (int*)(srcs2 + N_EDGES);

    size_t zero_bytes = (1024 + BATCH * HIDDEN + BATCH) * 4;
    hipMemsetAsync(bcnt, 0, zero_bytes, stream);

    const int* row = ei;
    const int* col = ei + N_EDGES;

    hist_kernel <<<PBLK, 256, 0, stream>>>(col, bcnt);
    scan_kernel <<<1, 1024, 0, stream>>>(bcnt, bstart, cursor, cstart);
    part_kernel <<<PBLK, 256, 0, stream>>>(row, col, cursor, part);
    sort2_kernel<<<NBUCK, 256, 0, stream>>>(part, bstart, bcnt, x, srcs2, cstart, dinv, xs);
    gather_pool_kernel<<<NCHUNK, 256, 0, stream>>>(cstart, srcs2, xs, dinv, batch,
                                                   Wc, bc, pooled, countsf);
    final_kernel<<<(BATCH * N_CLASSES + 255) / 256, 256, 0, stream>>>(pooled, countsf, Wl, bl, out);
}

// Round 6
// 249.504 us; speedup vs baseline: 1.5650x; 1.5650x over previous
//
#include <hip/hip_runtime.h>

#define N_NODES   1000000
#define N_EDGES   2000000
#define N_FEAT    11
#define HIDDEN    64
#define BATCH     128
#define N_CLASSES 19

#define NPB     1024                      // nodes per bucket (bucket = col>>10)
#define NBUCK   977                       // ceil(1e6/1024)
#define BCAP    2560                      // fixed edge capacity per bucket (mean 2048, +11 sigma)
#define EPB     4096                      // edges per partition block
#define PBLK    489                       // ceil(2e6/4096)
#define NSLOT   8                         // pool slots per 256-node chunk
#define NCHUNK  (NBUCK * 4)               // 3908 chunks of 256 nodes

// f32 -> bf16 round-to-nearest-even
__device__ __forceinline__ unsigned f2b(float v) {
    unsigned u = __float_as_uint(v);
    return (u + 0x7FFFu + ((u >> 16) & 1u)) >> 16;
}

// ---- K1: multisplit into fixed-capacity bucket regions (hist+scan fused away)
__global__ __launch_bounds__(256) void part_kernel(const int* __restrict__ row,
                                                   const int* __restrict__ col,
                                                   int* __restrict__ bcnt,
                                                   int* __restrict__ part) {
    __shared__ int lh[NPB];
    const int t = threadIdx.x;
    for (int i = t; i < NPB; i += 256) lh[i] = 0;
    __syncthreads();
    const int base = blockIdx.x * EPB;
#pragma unroll
    for (int i = 0; i < EPB / 256; ++i) {
        int e = base + i * 256 + t;
        if (e < N_EDGES) atomicAdd(&lh[col[e] >> 10], 1);
    }
    __syncthreads();
    for (int b = t; b < NBUCK; b += 256) {
        int v = lh[b];
        if (v) lh[b] = b * BCAP + atomicAdd(&bcnt[b], v);  // reserve region slice
    }
    __syncthreads();
#pragma unroll
    for (int i = 0; i < EPB / 256; ++i) {
        int e = base + i * 256 + t;
        if (e < N_EDGES) {
            int c = col[e];
            int pos = atomicAdd(&lh[c >> 10], 1);          // LDS cursor
            part[pos] = (row[e] << 10) | (c & (NPB - 1));
        }
    }
}

// ---- K2: per-bucket counting sort -> srcs/nstart/ndeg/cstart5 + dinv + bf16 xs
__global__ __launch_bounds__(256) void sort2_kernel(const int* __restrict__ part,
                                                    const int* __restrict__ bcnt,
                                                    const float* __restrict__ x,
                                                    int* __restrict__ srcs,
                                                    int* __restrict__ cstart5,
                                                    int* __restrict__ nstart,
                                                    unsigned short* __restrict__ ndeg,
                                                    float* __restrict__ dinv,
                                                    unsigned short* __restrict__ xs) {
    __shared__ int cnt[NPB];
    __shared__ int off[NPB];
    __shared__ int tsum[256];
    const int t = threadIdx.x, b = blockIdx.x;
    for (int i = t; i < NPB; i += 256) cnt[i] = 0;
    __syncthreads();
    const int s0 = b * BCAP, e0 = s0 + bcnt[b];
    for (int j = s0 + t; j < e0; j += 256)
        atomicAdd(&cnt[part[j] & (NPB - 1)], 1);
    __syncthreads();
    // exclusive scan of 1024 counts
    const int i0 = t * 4;
    int c0 = cnt[i0], c1 = cnt[i0 + 1], c2 = cnt[i0 + 2], c3 = cnt[i0 + 3];
    int s = c0 + c1 + c2 + c3;
    tsum[t] = s;
    __syncthreads();
    for (int o = 1; o < 256; o <<= 1) {
        int a = (t >= o) ? tsum[t - o] : 0;
        __syncthreads();
        tsum[t] += a;
        __syncthreads();
    }
    int ex = tsum[t] - s;
    off[i0] = ex; off[i0 + 1] = ex + c0; off[i0 + 2] = ex + c0 + c1; off[i0 + 3] = ex + c0 + c1 + c2;
    __syncthreads();
    if (t < 4) cstart5[b * 5 + t] = s0 + off[t * 256];
    if (t == 4) cstart5[b * 5 + 4] = e0;
    for (int i = t; i < NPB; i += 256) {
        int n = b * NPB + i;
        if (n < N_NODES) {
            int d = cnt[i];
            float dv = d ? rsqrtf((float)d) : 0.0f;
            dinv[n]   = dv;
            ndeg[n]   = (unsigned short)d;
            nstart[n] = s0 + off[i];
            const float* xr = x + (size_t)n * N_FEAT;
            unsigned h[11];
#pragma unroll
            for (int k = 0; k < 11; ++k) h[k] = f2b(dv * xr[k]);
            uint4 A, B;
            A.x = h[0] | (h[1] << 16); A.y = h[2] | (h[3] << 16);
            A.z = h[4] | (h[5] << 16); A.w = h[6] | (h[7] << 16);
            B.x = h[8] | (h[9] << 16); B.y = h[10]; B.z = 0u; B.w = 0u;
            uint4* o = (uint4*)(xs + (size_t)n * 16);
            o[0] = A; o[1] = B;
        }
    }
    __syncthreads();
    for (int j = s0 + t; j < e0; j += 256) {
        int p  = part[j];
        int cl = p & (NPB - 1);
        int pos = s0 + atomicAdd(&off[cl], 1);
        srcs[pos] = p >> 10;                    // plain source row id
    }
}

// ---- K3: degree-sorted register gather (bf16 xs) + transform/relu + mean-pool
__global__ __launch_bounds__(256) void gather_pool_kernel(
    const int* __restrict__ cstart5, const int* __restrict__ srcs,
    const unsigned short* __restrict__ xs, const int* __restrict__ nstart,
    const unsigned short* __restrict__ ndeg, const float* __restrict__ dinv,
    const int* __restrict__ batch, const float* __restrict__ Wc,
    const float* __restrict__ bc, float* __restrict__ pooled,
    float* __restrict__ countsf) {
    __shared__ float facc[256 * 12];        // 12 KB
    __shared__ int   sj0[256];
    __shared__ int   sdeg[256];
    __shared__ float sdinv[256];
    __shared__ int   sbid[256];
    __shared__ int   sperm[256];
    __shared__ int   dcnt[32];
    __shared__ int   doff[32];
    __shared__ float pbuf[NSLOT * HIDDEN];  // 2 KB
    __shared__ int   pcnt[NSLOT];
    const int t = threadIdx.x, lane = t & 63, w = t >> 6;
    const int base = blockIdx.x * 256;
    {
        int n = base + t;
        bool v = n < N_NODES;
        sj0[t]   = v ? nstart[n] : 0;
        sdeg[t]  = v ? (int)ndeg[n] : 0;
        sdinv[t] = v ? dinv[n] : 0.0f;
        sbid[t]  = v ? batch[n] : -1;
    }
    for (int i = t; i < NSLOT * HIDDEN; i += 256) pbuf[i] = 0.0f;
    if (t < NSLOT) pcnt[t] = 0;
    if (t < 32)    dcnt[t] = 0;
    __syncthreads();
    // LDS counting sort of 256 nodes by degree -> sperm (ascending degree)
    int mybin = sdeg[t] < 31 ? sdeg[t] : 31;
    atomicAdd(&dcnt[mybin], 1);
    __syncthreads();
    if (t < 32) {
        int r = 0;
        for (int i = 0; i < t; ++i) r += dcnt[i];
        doff[t] = r;
    }
    __syncthreads();
    int pos = atomicAdd(&doff[mybin], 1);
    sperm[pos] = t;
    __syncthreads();

    // phase A: thread t aggregates node sperm[t] (wave-uniform degrees)
    {
        int i  = sperm[t];
        int j0 = sj0[i], d = sdeg[i];
        float acc[11];
#pragma unroll
        for (int k = 0; k < 11; ++k) acc[k] = 0.0f;
        for (int j = j0; j < j0 + d; ++j) {
            int r = srcs[j];
            const uint4* xr = (const uint4*)(xs + (size_t)r * 16);
            uint4 A = xr[0];
            uint2 B = *(const uint2*)(xr + 1);
            acc[0]  += __uint_as_float(A.x << 16);
            acc[1]  += __uint_as_float(A.x & 0xFFFF0000u);
            acc[2]  += __uint_as_float(A.y << 16);
            acc[3]  += __uint_as_float(A.y & 0xFFFF0000u);
            acc[4]  += __uint_as_float(A.z << 16);
            acc[5]  += __uint_as_float(A.z & 0xFFFF0000u);
            acc[6]  += __uint_as_float(A.w << 16);
            acc[7]  += __uint_as_float(A.w & 0xFFFF0000u);
            acc[8]  += __uint_as_float(B.x << 16);
            acc[9]  += __uint_as_float(B.x & 0xFFFF0000u);
            acc[10] += __uint_as_float(B.y << 16);
        }
        float* f = &facc[i * 12];
#pragma unroll
        for (int k = 0; k < 11; ++k) f[k] = acc[k];
    }
    __syncthreads();

    // phase B: wave w owns nodes [w*64, w*64+64); lane = hidden channel
    float wk[N_FEAT];
#pragma unroll
    for (int k = 0; k < N_FEAT; ++k) wk[k] = Wc[k * HIDDEN + lane];
    const float bias = bc[lane];
    const int bid0 = sbid[0];
    int cur = -1; float accp = 0.0f; int cntp = 0;
    for (int i = w * 64; i < w * 64 + 64; ++i) {
        int bid = sbid[i];
        if (bid < 0) break;
        if (bid != cur) {
            if (cur >= 0) {
                int slot = cur - bid0;
                if (slot >= 0 && slot < NSLOT) {
                    atomicAdd(&pbuf[slot * HIDDEN + lane], accp);
                    if (lane == 0) atomicAdd(&pcnt[slot], cntp);
                } else {
                    atomicAdd(&pooled[(size_t)cur * HIDDEN + lane], accp);
                    if (lane == 0) atomicAdd(&countsf[cur], (float)cntp);
                }
            }
            cur = bid; accp = 0.0f; cntp = 0;
        }
        float s = 0.0f;
#pragma unroll
        for (int k = 0; k < N_FEAT; ++k)
            s = fmaf(wk[k], facc[i * 12 + k], s);    // LDS broadcast
        accp += fmaxf(fmaf(sdinv[i], s, bias), 0.0f);
        ++cntp;
    }
    if (cur >= 0) {
        int slot = cur - bid0;
        if (slot >= 0 && slot < NSLOT) {
            atomicAdd(&pbuf[slot * HIDDEN + lane], accp);
            if (lane == 0) atomicAdd(&pcnt[slot], cntp);
        } else {
            atomicAdd(&pooled[(size_t)cur * HIDDEN + lane], accp);
            if (lane == 0) atomicAdd(&countsf[cur], (float)cntp);
        }
    }
    __syncthreads();
    for (int s = w; s < NSLOT; s += 4) {
        int c = pcnt[s];
        if (c > 0) {
            atomicAdd(&pooled[(size_t)(bid0 + s) * HIDDEN + lane], pbuf[s * HIDDEN + lane]);
            if (lane == 0) atomicAdd(&countsf[bid0 + s], (float)c);
        }
    }
}

// ---- K4: out = (pooled/cnt) @ W_lin + b_lin ----
__global__ void final_kernel(const float* __restrict__ pooled, const float* __restrict__ counts,
                             const float* __restrict__ Wl, const float* __restrict__ bl,
                             float* __restrict__ out) {
    int i = blockIdx.x * blockDim.x + threadIdx.x;
    if (i >= BATCH * N_CLASSES) return;
    int b = i / N_CLASSES;
    int c = i - b * N_CLASSES;
    float inv = 1.0f / fmaxf(counts[b], 1.0f);
    float s = bl[c];
#pragma unroll 8
    for (int h = 0; h < HIDDEN; ++h)
        s = fmaf(pooled[b * HIDDEN + h] * inv, Wl[h * N_CLASSES + c], s);
    out[i] = s;
}

extern "C" void kernel_launch(void* const* d_in, const int* in_sizes, int n_in,
                              void* d_out, int out_size, void* d_ws, size_t ws_size,
                              hipStream_t stream) {
    // inputs: x, edge_index, y(unused), batch, W_conv, b_conv, W_lin, b_lin
    const float* x     = (const float*)d_in[0];
    const int*   ei    = (const int*)d_in[1];   // [2, E] int32
    const int*   batch = (const int*)d_in[3];
    const float* Wc    = (const float*)d_in[4];
    const float* bc    = (const float*)d_in[5];
    const float* Wl    = (const float*)d_in[6];
    const float* bl    = (const float*)d_in[7];
    float*       out   = (float*)d_out;

    // ws: [bcnt 1024][pooled 8192][countsf 128] (zeroed) | cstart5[4896] |
    //     xs[16M ushort] | nstart[1M] | ndeg[1M ushort] | dinv[1M] |
    //     part[NBUCK*BCAP] | srcs[NBUCK*BCAP]            (~62 MB)
    int*            bcnt    = (int*)d_ws;
    float*          pooled  = (float*)(bcnt + 1024);
    float*          countsf = pooled + BATCH * HIDDEN;
    int*            cstart5 = (int*)(countsf + BATCH);
    unsigned short* xs      = (unsigned short*)(cstart5 + 4896);
    int*            nstart  = (int*)(xs + (size_t)N_NODES * 16);
    unsigned short* ndeg    = (unsigned short*)(nstart + N_NODES);
    float*          dinv    = (float*)(ndeg + N_NODES);
    int*            part    = (int*)(dinv + N_NODES);
    int*            srcs    = part + (size_t)NBUCK * BCAP;

    size_t zero_bytes = (1024 + BATCH * HIDDEN + BATCH) * 4;
    hipMemsetAsync(d_ws, 0, zero_bytes, stream);

    const int* row = ei;
    const int* col = ei + N_EDGES;

    part_kernel <<<PBLK, 256, 0, stream>>>(row, col, bcnt, part);
    sort2_kernel<<<NBUCK, 256, 0, stream>>>(part, bcnt, x, srcs, cstart5, nstart, ndeg, dinv, xs);
    gather_pool_kernel<<<NCHUNK, 256, 0, stream>>>(cstart5, srcs, xs, nstart, ndeg, dinv,
                                                   batch, Wc, bc, pooled, countsf);
    final_kernel<<<(BATCH * N_CLASSES + 255) / 256, 256, 0, stream>>>(pooled, countsf, Wl, bl, out);
}

// Round 8
// 244.864 us; speedup vs baseline: 1.5947x; 1.0190x over previous
//
#include <hip/hip_runtime.h>

#define N_NODES   1000000
#define N_EDGES   2000000
#define N_FEAT    11
#define HIDDEN    64
#define BATCH     128
#define N_CLASSES 19

#define NPB     2048                      // nodes per bucket (bucket = col>>11)
#define NBUCK   489                       // ceil(1e6/2048)
#define BCAP    5120                      // edges per bucket region (mean ~4090, +16 sigma)
#define EPB     8192                      // edges per partition block
#define PBLK    245                       // ceil(2e6/8192)
#define NSLOT   8                         // pool slots per 256-node chunk
#define NCHUNK  3907                      // ceil(1e6/256)
#define FSTR    13                        // facc stride (coprime with 32 banks)

// f32 -> bf16 round-to-nearest-even
__device__ __forceinline__ unsigned f2b(float v) {
    unsigned u = __float_as_uint(v);
    return (u + 0x7FFFu + ((u >> 16) & 1u)) >> 16;
}

// ---- K1: multisplit into fixed-capacity bucket regions ----
// EPB=8192 & NPB=2048 -> ~16 edges per (block,bucket) slice = full 64B lines.
__global__ __launch_bounds__(256) void part_kernel(const int* __restrict__ row,
                                                   const int* __restrict__ col,
                                                   int* __restrict__ bcnt,
                                                   int* __restrict__ part) {
    __shared__ int lh[512];
    const int t = threadIdx.x;
    for (int i = t; i < 512; i += 256) lh[i] = 0;   // FIX: zero ALL 512 slots
    __syncthreads();
    const int q0 = (blockIdx.x * EPB) >> 2;         // int4 index base
    const int4* col4 = (const int4*)col;
    const int4* row4 = (const int4*)row;
#pragma unroll
    for (int i = 0; i < EPB / 1024; ++i) {          // 8 int4 per thread
        int q = q0 + i * 256 + t;
        if (q < N_EDGES / 4) {
            int4 c = col4[q];
            atomicAdd(&lh[c.x >> 11], 1); atomicAdd(&lh[c.y >> 11], 1);
            atomicAdd(&lh[c.z >> 11], 1); atomicAdd(&lh[c.w >> 11], 1);
        }
    }
    __syncthreads();
    for (int b = t; b < NBUCK; b += 256) {
        int v = lh[b];
        if (v) lh[b] = b * BCAP + atomicAdd(&bcnt[b], v);   // reserve contiguous slice
    }
    __syncthreads();
#pragma unroll
    for (int i = 0; i < EPB / 1024; ++i) {
        int q = q0 + i * 256 + t;
        if (q < N_EDGES / 4) {
            int4 c = col4[q];
            int4 r = row4[q];
            int p;
            p = atomicAdd(&lh[c.x >> 11], 1); part[p] = (r.x << 11) | (c.x & (NPB - 1));
            p = atomicAdd(&lh[c.y >> 11], 1); part[p] = (r.y << 11) | (c.y & (NPB - 1));
            p = atomicAdd(&lh[c.z >> 11], 1); part[p] = (r.z << 11) | (c.z & (NPB - 1));
            p = atomicAdd(&lh[c.w >> 11], 1); part[p] = (r.w << 11) | (c.w & (NPB - 1));
        }
    }
}

// ---- K2: per-bucket counting sort -> srcs/nstart/ndeg + dinv + bf16 xs ----
__global__ __launch_bounds__(256) void sort2_kernel(const int* __restrict__ part,
                                                    const int* __restrict__ bcnt,
                                                    const float* __restrict__ x,
                                                    int* __restrict__ srcs,
                                                    int* __restrict__ nstart,
                                                    unsigned short* __restrict__ ndeg,
                                                    float* __restrict__ dinv,
                                                    unsigned short* __restrict__ xs) {
    __shared__ int cnt[NPB];       // 8 KB
    __shared__ int off[NPB];       // 8 KB
    __shared__ int tsum[256];
    const int t = threadIdx.x, b = blockIdx.x;
    for (int i = t; i < NPB; i += 256) cnt[i] = 0;
    __syncthreads();
    const int s0 = b * BCAP, e0 = s0 + bcnt[b];
    for (int j = s0 + t; j < e0; j += 256)
        atomicAdd(&cnt[part[j] & (NPB - 1)], 1);
    __syncthreads();
    // exclusive scan of 2048 counts: 8/thread + Hillis-Steele over thread sums
    const int i0 = t * 8;
    int c[8], s = 0;
#pragma unroll
    for (int q = 0; q < 8; ++q) { c[q] = cnt[i0 + q]; s += c[q]; }
    tsum[t] = s;
    __syncthreads();
    for (int o = 1; o < 256; o <<= 1) {
        int a = (t >= o) ? tsum[t - o] : 0;
        __syncthreads();
        tsum[t] += a;
        __syncthreads();
    }
    int run = tsum[t] - s;
#pragma unroll
    for (int q = 0; q < 8; ++q) { off[i0 + q] = run; run += c[q]; }
    __syncthreads();
    // per-node outputs + fused xpad (bf16, 32B rows), coalesced
    for (int i = t; i < NPB; i += 256) {
        int n = b * NPB + i;
        if (n < N_NODES) {
            int d = cnt[i];
            float dv = d ? rsqrtf((float)d) : 0.0f;
            dinv[n]   = dv;
            ndeg[n]   = (unsigned short)d;
            nstart[n] = s0 + off[i];
            const float* xr = x + (size_t)n * N_FEAT;
            unsigned h[11];
#pragma unroll
            for (int k = 0; k < 11; ++k) h[k] = f2b(dv * xr[k]);
            uint4 A, B;
            A.x = h[0] | (h[1] << 16); A.y = h[2] | (h[3] << 16);
            A.z = h[4] | (h[5] << 16); A.w = h[6] | (h[7] << 16);
            B.x = h[8] | (h[9] << 16); B.y = h[10]; B.z = 0u; B.w = 0u;
            uint4* o = (uint4*)(xs + (size_t)n * 16);
            o[0] = A; o[1] = B;
        }
    }
    __syncthreads();
    // scatter to node-sorted order
    for (int j = s0 + t; j < e0; j += 256) {
        int p  = part[j];
        int cl = p & (NPB - 1);
        int pos = s0 + atomicAdd(&off[cl], 1);
        srcs[pos] = p >> 11;
    }
}

// ---- K3: degree-sorted register gather (bf16 xs) + transform/relu + mean-pool
__global__ __launch_bounds__(256) void gather_pool_kernel(
    const int* __restrict__ srcs, const unsigned short* __restrict__ xs,
    const int* __restrict__ nstart, const unsigned short* __restrict__ ndeg,
    const float* __restrict__ dinv, const int* __restrict__ batch,
    const float* __restrict__ Wc, const float* __restrict__ bc,
    float* __restrict__ pooled, float* __restrict__ countsf) {
    __shared__ float facc[256 * FSTR];      // 13.3 KB
    __shared__ int   sj0[256];
    __shared__ int   sdeg[256];
    __shared__ float sdinv[256];
    __shared__ int   sbid[256];
    __shared__ int   sperm[256];
    __shared__ int   dcnt[32];
    __shared__ int   doff[32];
    __shared__ float pbuf[NSLOT * HIDDEN];  // 2 KB
    __shared__ int   pcnt[NSLOT];
    const int t = threadIdx.x, lane = t & 63, w = t >> 6;
    const int base = blockIdx.x * 256;
    {
        int n = base + t;
        bool v = n < N_NODES;
        sj0[t]   = v ? nstart[n] : 0;
        sdeg[t]  = v ? (int)ndeg[n] : 0;
        sdinv[t] = v ? dinv[n] : 0.0f;
        sbid[t]  = v ? batch[n] : -1;
    }
    for (int i = t; i < NSLOT * HIDDEN; i += 256) pbuf[i] = 0.0f;
    if (t < NSLOT) pcnt[t] = 0;
    if (t < 32)    dcnt[t] = 0;
    __syncthreads();
    // LDS counting sort of 256 nodes by degree -> sperm
    int mybin = sdeg[t] < 31 ? sdeg[t] : 31;
    atomicAdd(&dcnt[mybin], 1);
    __syncthreads();
    if (t < 32) {
        int r = 0;
        for (int i = 0; i < t; ++i) r += dcnt[i];
        doff[t] = r;
    }
    __syncthreads();
    int pos = atomicAdd(&doff[mybin], 1);
    sperm[pos] = t;
    __syncthreads();

    // phase A: thread t aggregates node sperm[t] (wave-uniform degrees)
    {
        int i  = sperm[t];
        int j0 = sj0[i], d = sdeg[i];
        float acc[11];
#pragma unroll
        for (int k = 0; k < 11; ++k) acc[k] = 0.0f;
        for (int j = j0; j < j0 + d; ++j) {
            int r = srcs[j];
            const uint4* xr = (const uint4*)(xs + (size_t)r * 16);
            uint4 A = xr[0];
            uint2 B = *(const uint2*)(xr + 1);
            acc[0]  += __uint_as_float(A.x << 16);
            acc[1]  += __uint_as_float(A.x & 0xFFFF0000u);
            acc[2]  += __uint_as_float(A.y << 16);
            acc[3]  += __uint_as_float(A.y & 0xFFFF0000u);
            acc[4]  += __uint_as_float(A.z << 16);
            acc[5]  += __uint_as_float(A.z & 0xFFFF0000u);
            acc[6]  += __uint_as_float(A.w << 16);
            acc[7]  += __uint_as_float(A.w & 0xFFFF0000u);
            acc[8]  += __uint_as_float(B.x << 16);
            acc[9]  += __uint_as_float(B.x & 0xFFFF0000u);
            acc[10] += __uint_as_float(B.y << 16);
        }
        float* f = &facc[i * FSTR];
#pragma unroll
        for (int k = 0; k < 11; ++k) f[k] = acc[k];   // stride 13: conflict-free
    }
    __syncthreads();

    // phase B: wave w owns nodes [w*64, w*64+64); lane = hidden channel
    float wk[N_FEAT];
#pragma unroll
    for (int k = 0; k < N_FEAT; ++k) wk[k] = Wc[k * HIDDEN + lane];
    const float bias = bc[lane];
    const int bid0 = sbid[0];
    int cur = -1; float accp = 0.0f; int cntp = 0;
    for (int i = w * 64; i < w * 64 + 64; ++i) {
        int bid = sbid[i];
        if (bid < 0) break;
        if (bid != cur) {
            if (cur >= 0) {
                int slot = cur - bid0;
                if (slot >= 0 && slot < NSLOT) {
                    atomicAdd(&pbuf[slot * HIDDEN + lane], accp);
                    if (lane == 0) atomicAdd(&pcnt[slot], cntp);
                } else {
                    atomicAdd(&pooled[(size_t)cur * HIDDEN + lane], accp);
                    if (lane == 0) atomicAdd(&countsf[cur], (float)cntp);
                }
            }
            cur = bid; accp = 0.0f; cntp = 0;
        }
        float s = 0.0f;
#pragma unroll
        for (int k = 0; k < N_FEAT; ++k)
            s = fmaf(wk[k], facc[i * FSTR + k], s);   // LDS broadcast
        accp += fmaxf(fmaf(sdinv[i], s, bias), 0.0f);
        ++cntp;
    }
    if (cur >= 0) {
        int slot = cur - bid0;
        if (slot >= 0 && slot < NSLOT) {
            atomicAdd(&pbuf[slot * HIDDEN + lane], accp);
            if (lane == 0) atomicAdd(&pcnt[slot], cntp);
        } else {
            atomicAdd(&pooled[(size_t)cur * HIDDEN + lane], accp);
            if (lane == 0) atomicAdd(&countsf[cur], (float)cntp);
        }
    }
    __syncthreads();
    for (int s = w; s < NSLOT; s += 4) {
        int c = pcnt[s];
        if (c > 0) {
            atomicAdd(&pooled[(size_t)(bid0 + s) * HIDDEN + lane], pbuf[s * HIDDEN + lane]);
            if (lane == 0) atomicAdd(&countsf[bid0 + s], (float)c);
        }
    }
}

// ---- K4: out = (pooled/cnt) @ W_lin + b_lin ----
__global__ void final_kernel(const float* __restrict__ pooled, const float* __restrict__ counts,
                             const float* __restrict__ Wl, const float* __restrict__ bl,
                             float* __restrict__ out) {
    int i = blockIdx.x * blockDim.x + threadIdx.x;
    if (i >= BATCH * N_CLASSES) return;
    int b = i / N_CLASSES;
    int c = i - b * N_CLASSES;
    float inv = 1.0f / fmaxf(counts[b], 1.0f);
    float s = bl[c];
#pragma unroll 8
    for (int h = 0; h < HIDDEN; ++h)
        s = fmaf(pooled[b * HIDDEN + h] * inv, Wl[h * N_CLASSES + c], s);
    out[i] = s;
}

extern "C" void kernel_launch(void* const* d_in, const int* in_sizes, int n_in,
                              void* d_out, int out_size, void* d_ws, size_t ws_size,
                              hipStream_t stream) {
    // inputs: x, edge_index, y(unused), batch, W_conv, b_conv, W_lin, b_lin
    const float* x     = (const float*)d_in[0];
    const int*   ei    = (const int*)d_in[1];   // [2, E] int32
    const int*   batch = (const int*)d_in[3];
    const float* Wc    = (const float*)d_in[4];
    const float* bc    = (const float*)d_in[5];
    const float* Wl    = (const float*)d_in[6];
    const float* bl    = (const float*)d_in[7];
    float*       out   = (float*)d_out;

    // ws: [bcnt 512][pooled 8192][countsf 128] (zeroed, 35 KB) | xs[16M ushort] |
    //     nstart[1M] | ndeg[1M ushort] | dinv[1M] | part[489*5120] | srcs[489*5120]
    int*            bcnt    = (int*)d_ws;
    float*          pooled  = (float*)(bcnt + 512);
    float*          countsf = pooled + BATCH * HIDDEN;
    unsigned short* xs      = (unsigned short*)(countsf + BATCH);
    int*            nstart  = (int*)(xs + (size_t)N_NODES * 16);
    unsigned short* ndeg    = (unsigned short*)(nstart + N_NODES);
    float*          dinv    = (float*)(ndeg + N_NODES);
    int*            part    = (int*)(dinv + N_NODES);
    int*            srcs    = part + (size_t)NBUCK * BCAP;

    size_t zero_bytes = (512 + BATCH * HIDDEN + BATCH) * 4;
    hipMemsetAsync(d_ws, 0, zero_bytes, stream);

    const int* row = ei;
    const int* col = ei + N_EDGES;

    part_kernel <<<PBLK, 256, 0, stream>>>(row, col, bcnt, part);
    sort2_kernel<<<NBUCK, 256, 0, stream>>>(part, bcnt, x, srcs, nstart, ndeg, dinv, xs);
    gather_pool_kernel<<<NCHUNK, 256, 0, stream>>>(srcs, xs, nstart, ndeg, dinv,
                                                   batch, Wc, bc, pooled, countsf);
    final_kernel<<<(BATCH * N_CLASSES + 255) / 256, 256, 0, stream>>>(pooled, countsf, Wl, bl, out);
}

// Round 9
// 231.714 us; speedup vs baseline: 1.6852x; 1.0567x over previous
//
#include <hip/hip_runtime.h>

#define N_NODES   1000000
#define N_EDGES   2000000
#define N_FEAT    11
#define HIDDEN    64
#define BATCH     128
#define N_CLASSES 19

#define NPB     2048                      // nodes per bucket (bucket = col>>11)
#define NBUCK   489                       // ceil(1e6/2048)
#define BCAP    5120                      // edges per bucket region (mean ~4090, +16 sigma)
#define EPB     8192                      // edges per partition block
#define PBLK    245                       // ceil(2e6/8192)
#define NSLOT   8                         // pool slots per 256-node chunk
#define NCHUNK  3907                      // ceil(1e6/256)
#define FSTR    12                        // facc stride (R6 config: VGPR 20, occ 69%)

// f32 -> bf16 round-to-nearest-even
__device__ __forceinline__ unsigned f2b(float v) {
    unsigned u = __float_as_uint(v);
    return (u + 0x7FFFu + ((u >> 16) & 1u)) >> 16;
}

// ---- K1: multisplit into fixed-capacity bucket regions ----
// 1024 threads (16 waves) per block for latency hiding; 8 edges/thread.
__global__ __launch_bounds__(1024) void part_kernel(const int* __restrict__ row,
                                                    const int* __restrict__ col,
                                                    int* __restrict__ bcnt,
                                                    int* __restrict__ part) {
    __shared__ int lh[512];
    const int t = threadIdx.x;
    if (t < 512) lh[t] = 0;
    __syncthreads();
    const int q0 = (blockIdx.x * EPB) >> 2;         // int4 index base
    const int4* col4 = (const int4*)col;
    const int4* row4 = (const int4*)row;
#pragma unroll
    for (int i = 0; i < EPB / 4096; ++i) {          // 2 int4 per thread
        int q = q0 + i * 1024 + t;
        if (q < N_EDGES / 4) {
            int4 c = col4[q];
            atomicAdd(&lh[c.x >> 11], 1); atomicAdd(&lh[c.y >> 11], 1);
            atomicAdd(&lh[c.z >> 11], 1); atomicAdd(&lh[c.w >> 11], 1);
        }
    }
    __syncthreads();
    if (t < NBUCK) {
        int v = lh[t];
        if (v) lh[t] = t * BCAP + atomicAdd(&bcnt[t], v);   // reserve contiguous slice
    }
    __syncthreads();
#pragma unroll
    for (int i = 0; i < EPB / 4096; ++i) {
        int q = q0 + i * 1024 + t;
        if (q < N_EDGES / 4) {
            int4 c = col4[q];
            int4 r = row4[q];
            int p;
            p = atomicAdd(&lh[c.x >> 11], 1); part[p] = (r.x << 11) | (c.x & (NPB - 1));
            p = atomicAdd(&lh[c.y >> 11], 1); part[p] = (r.y << 11) | (c.y & (NPB - 1));
            p = atomicAdd(&lh[c.z >> 11], 1); part[p] = (r.z << 11) | (c.z & (NPB - 1));
            p = atomicAdd(&lh[c.w >> 11], 1); part[p] = (r.w << 11) | (c.w & (NPB - 1));
        }
    }
}

// ---- K2: per-bucket counting sort -> srcs/nstart/ndeg + dinv + bf16 xs ----
// 512 threads (8 waves) per block for latency hiding.
__global__ __launch_bounds__(512) void sort2_kernel(const int* __restrict__ part,
                                                    const int* __restrict__ bcnt,
                                                    const float* __restrict__ x,
                                                    int* __restrict__ srcs,
                                                    int* __restrict__ nstart,
                                                    unsigned short* __restrict__ ndeg,
                                                    float* __restrict__ dinv,
                                                    unsigned short* __restrict__ xs) {
    __shared__ int cnt[NPB];       // 8 KB
    __shared__ int off[NPB];       // 8 KB
    __shared__ int tsum[512];
    const int t = threadIdx.x, b = blockIdx.x;
    for (int i = t; i < NPB; i += 512) cnt[i] = 0;
    __syncthreads();
    const int s0 = b * BCAP, e0 = s0 + bcnt[b];
    for (int j = s0 + t; j < e0; j += 512)
        atomicAdd(&cnt[part[j] & (NPB - 1)], 1);
    __syncthreads();
    // exclusive scan of 2048 counts: 4/thread + Hillis-Steele over 512 thread sums
    const int i0 = t * 4;
    int c[4], s = 0;
#pragma unroll
    for (int q = 0; q < 4; ++q) { c[q] = cnt[i0 + q]; s += c[q]; }
    tsum[t] = s;
    __syncthreads();
    for (int o = 1; o < 512; o <<= 1) {
        int a = (t >= o) ? tsum[t - o] : 0;
        __syncthreads();
        tsum[t] += a;
        __syncthreads();
    }
    int run = tsum[t] - s;
#pragma unroll
    for (int q = 0; q < 4; ++q) { off[i0 + q] = run; run += c[q]; }
    __syncthreads();
    // per-node outputs + fused xpad (bf16, 32B rows), coalesced
    for (int i = t; i < NPB; i += 512) {
        int n = b * NPB + i;
        if (n < N_NODES) {
            int d = cnt[i];
            float dv = d ? rsqrtf((float)d) : 0.0f;
            dinv[n]   = dv;
            ndeg[n]   = (unsigned short)d;
            nstart[n] = s0 + off[i];
            const float* xr = x + (size_t)n * N_FEAT;
            unsigned h[11];
#pragma unroll
            for (int k = 0; k < 11; ++k) h[k] = f2b(dv * xr[k]);
            uint4 A, B;
            A.x = h[0] | (h[1] << 16); A.y = h[2] | (h[3] << 16);
            A.z = h[4] | (h[5] << 16); A.w = h[6] | (h[7] << 16);
            B.x = h[8] | (h[9] << 16); B.y = h[10]; B.z = 0u; B.w = 0u;
            uint4* o = (uint4*)(xs + (size_t)n * 16);
            o[0] = A; o[1] = B;
        }
    }
    __syncthreads();
    // scatter to node-sorted order
    for (int j = s0 + t; j < e0; j += 512) {
        int p  = part[j];
        int cl = p & (NPB - 1);
        int pos = s0 + atomicAdd(&off[cl], 1);
        srcs[pos] = p >> 11;
    }
}

// ---- K3: degree-sorted register gather (bf16 xs) + transform/relu + mean-pool
__global__ __launch_bounds__(256) void gather_pool_kernel(
    const int* __restrict__ srcs, const unsigned short* __restrict__ xs,
    const int* __restrict__ nstart, const unsigned short* __restrict__ ndeg,
    const float* __restrict__ dinv, const int* __restrict__ batch,
    const float* __restrict__ Wc, const float* __restrict__ bc,
    float* __restrict__ pooled, float* __restrict__ countsf) {
    __shared__ float facc[256 * FSTR];      // 12 KB
    __shared__ int   sj0[256];
    __shared__ int   sdeg[256];
    __shared__ float sdinv[256];
    __shared__ int   sbid[256];
    __shared__ int   sperm[256];
    __shared__ int   dcnt[32];
    __shared__ int   doff[32];
    __shared__ float pbuf[NSLOT * HIDDEN];  // 2 KB
    __shared__ int   pcnt[NSLOT];
    const int t = threadIdx.x, lane = t & 63, w = t >> 6;
    const int base = blockIdx.x * 256;
    {
        int n = base + t;
        bool v = n < N_NODES;
        sj0[t]   = v ? nstart[n] : 0;
        sdeg[t]  = v ? (int)ndeg[n] : 0;
        sdinv[t] = v ? dinv[n] : 0.0f;
        sbid[t]  = v ? batch[n] : -1;
    }
    for (int i = t; i < NSLOT * HIDDEN; i += 256) pbuf[i] = 0.0f;
    if (t < NSLOT) pcnt[t] = 0;
    if (t < 32)    dcnt[t] = 0;
    __syncthreads();
    // LDS counting sort of 256 nodes by degree -> sperm
    int mybin = sdeg[t] < 31 ? sdeg[t] : 31;
    atomicAdd(&dcnt[mybin], 1);
    __syncthreads();
    if (t < 32) {
        int r = 0;
        for (int i = 0; i < t; ++i) r += dcnt[i];
        doff[t] = r;
    }
    __syncthreads();
    int pos = atomicAdd(&doff[mybin], 1);
    sperm[pos] = t;
    __syncthreads();

    // phase A: thread t aggregates node sperm[t] (wave-uniform degrees)
    {
        int i  = sperm[t];
        int j0 = sj0[i], d = sdeg[i];
        float acc[11];
#pragma unroll
        for (int k = 0; k < 11; ++k) acc[k] = 0.0f;
        for (int j = j0; j < j0 + d; ++j) {
            int r = srcs[j];
            const uint4* xr = (const uint4*)(xs + (size_t)r * 16);
            uint4 A = xr[0];
            uint2 B = *(const uint2*)(xr + 1);
            acc[0]  += __uint_as_float(A.x << 16);
            acc[1]  += __uint_as_float(A.x & 0xFFFF0000u);
            acc[2]  += __uint_as_float(A.y << 16);
            acc[3]  += __uint_as_float(A.y & 0xFFFF0000u);
            acc[4]  += __uint_as_float(A.z << 16);
            acc[5]  += __uint_as_float(A.z & 0xFFFF0000u);
            acc[6]  += __uint_as_float(A.w << 16);
            acc[7]  += __uint_as_float(A.w & 0xFFFF0000u);
            acc[8]  += __uint_as_float(B.x << 16);
            acc[9]  += __uint_as_float(B.x & 0xFFFF0000u);
            acc[10] += __uint_as_float(B.y << 16);
        }
        float* f = &facc[i * FSTR];
#pragma unroll
        for (int k = 0; k < 11; ++k) f[k] = acc[k];
    }
    __syncthreads();

    // phase B: wave w owns nodes [w*64, w*64+64); lane = hidden channel
    float wk[N_FEAT];
#pragma unroll
    for (int k = 0; k < N_FEAT; ++k) wk[k] = Wc[k * HIDDEN + lane];
    const float bias = bc[lane];
    const int bid0 = sbid[0];
    int cur = -1; float accp = 0.0f; int cntp = 0;
    for (int i = w * 64; i < w * 64 + 64; ++i) {
        int bid = sbid[i];
        if (bid < 0) break;
        if (bid != cur) {
            if (cur >= 0) {
                int slot = cur - bid0;
                if (slot >= 0 && slot < NSLOT) {
                    atomicAdd(&pbuf[slot * HIDDEN + lane], accp);
                    if (lane == 0) atomicAdd(&pcnt[slot], cntp);
                } else {
                    atomicAdd(&pooled[(size_t)cur * HIDDEN + lane], accp);
                    if (lane == 0) atomicAdd(&countsf[cur], (float)cntp);
                }
            }
            cur = bid; accp = 0.0f; cntp = 0;
        }
        float s = 0.0f;
#pragma unroll
        for (int k = 0; k < N_FEAT; ++k)
            s = fmaf(wk[k], facc[i * FSTR + k], s);   // LDS broadcast
        accp += fmaxf(fmaf(sdinv[i], s, bias), 0.0f);
        ++cntp;
    }
    if (cur >= 0) {
        int slot = cur - bid0;
        if (slot >= 0 && slot < NSLOT) {
            atomicAdd(&pbuf[slot * HIDDEN + lane], accp);
            if (lane == 0) atomicAdd(&pcnt[slot], cntp);
        } else {
            atomicAdd(&pooled[(size_t)cur * HIDDEN + lane], accp);
            if (lane == 0) atomicAdd(&countsf[cur], (float)cntp);
        }
    }
    __syncthreads();
    for (int s = w; s < NSLOT; s += 4) {
        int c = pcnt[s];
        if (c > 0) {
            atomicAdd(&pooled[(size_t)(bid0 + s) * HIDDEN + lane], pbuf[s * HIDDEN + lane]);
            if (lane == 0) atomicAdd(&countsf[bid0 + s], (float)c);
        }
    }
}

// ---- K4: out = (pooled/cnt) @ W_lin + b_lin ----
__global__ void final_kernel(const float* __restrict__ pooled, const float* __restrict__ counts,
                             const float* __restrict__ Wl, const float* __restrict__ bl,
                             float* __restrict__ out) {
    int i = blockIdx.x * blockDim.x + threadIdx.x;
    if (i >= BATCH * N_CLASSES) return;
    int b = i / N_CLASSES;
    int c = i - b * N_CLASSES;
    float inv = 1.0f / fmaxf(counts[b], 1.0f);
    float s = bl[c];
#pragma unroll 8
    for (int h = 0; h < HIDDEN; ++h)
        s = fmaf(pooled[b * HIDDEN + h] * inv, Wl[h * N_CLASSES + c], s);
    out[i] = s;
}

extern "C" void kernel_launch(void* const* d_in, const int* in_sizes, int n_in,
                              void* d_out, int out_size, void* d_ws, size_t ws_size,
                              hipStream_t stream) {
    // inputs: x, edge_index, y(unused), batch, W_conv, b_conv, W_lin, b_lin
    const float* x     = (const float*)d_in[0];
    const int*   ei    = (const int*)d_in[1];   // [2, E] int32
    const int*   batch = (const int*)d_in[3];
    const float* Wc    = (const float*)d_in[4];
    const float* bc    = (const float*)d_in[5];
    const float* Wl    = (const float*)d_in[6];
    const float* bl    = (const float*)d_in[7];
    float*       out   = (float*)d_out;

    // ws: [bcnt 512][pooled 8192][countsf 128] (zeroed, 35 KB) | xs[16M ushort] |
    //     nstart[1M] | ndeg[1M ushort] | dinv[1M] | part[489*5120] | srcs[489*5120]
    int*            bcnt    = (int*)d_ws;
    float*          pooled  = (float*)(bcnt + 512);
    float*          countsf = pooled + BATCH * HIDDEN;
    unsigned short* xs      = (unsigned short*)(countsf + BATCH);
    int*            nstart  = (int*)(xs + (size_t)N_NODES * 16);
    unsigned short* ndeg    = (unsigned short*)(nstart + N_NODES);
    float*          dinv    = (float*)(ndeg + N_NODES);
    int*            part    = (int*)(dinv + N_NODES);
    int*            srcs    = part + (size_t)NBUCK * BCAP;

    size_t zero_bytes = (512 + BATCH * HIDDEN + BATCH) * 4;
    hipMemsetAsync(d_ws, 0, zero_bytes, stream);

    const int* row = ei;
    const int* col = ei + N_EDGES;

    part_kernel <<<PBLK, 1024, 0, stream>>>(row, col, bcnt, part);
    sort2_kernel<<<NBUCK, 512, 0, stream>>>(part, bcnt, x, srcs, nstart, ndeg, dinv, xs);
    gather_pool_kernel<<<NCHUNK, 256, 0, stream>>>(srcs, xs, nstart, ndeg, dinv,
                                                   batch, Wc, bc, pooled, countsf);
    final_kernel<<<(BATCH * N_CLASSES + 255) / 256, 256, 0, stream>>>(pooled, countsf, Wl, bl, out);
}

// Round 10
// 230.677 us; speedup vs baseline: 1.6927x; 1.0045x over previous
//
#include <hip/hip_runtime.h>

#define N_NODES   1000000
#define N_EDGES   2000000
#define N_FEAT    11
#define HIDDEN    64
#define BATCH     128
#define N_CLASSES 19

#define NPB     2048                      // nodes per bucket (bucket = col>>11)
#define NBUCK   489                       // ceil(1e6/2048)
#define BCAP    5120                      // edges per bucket region (mean ~4090, +16 sigma)
#define EPB     8192                      // edges per partition block
#define PBLK    245                       // ceil(2e6/8192)
#define NSLOT   8                         // pool slots per 256-node chunk
#define NCHUNK  3907                      // ceil(1e6/256)
#define FSTR    12                        // facc stride (VGPR 20, occ ~70%)

// f32 -> bf16 round-to-nearest-even
__device__ __forceinline__ unsigned f2b(float v) {
    unsigned u = __float_as_uint(v);
    return (u + 0x7FFFu + ((u >> 16) & 1u)) >> 16;
}

// ---- K1: multisplit into fixed-capacity bucket regions ----
// single pass: edges held in registers across the histogram barrier.
__global__ __launch_bounds__(1024) void part_kernel(const int* __restrict__ row,
                                                    const int* __restrict__ col,
                                                    int* __restrict__ bcnt,
                                                    int* __restrict__ part) {
    __shared__ int lh[512];
    const int t = threadIdx.x;
    if (t < 512) lh[t] = 0;
    __syncthreads();
    const int q0 = (blockIdx.x * EPB) >> 2;         // int4 index base
    const int4* col4 = (const int4*)col;
    const int4* row4 = (const int4*)row;
    const int qa = q0 + t, qb = q0 + 1024 + t;
    const bool va = qa < N_EDGES / 4, vb = qb < N_EDGES / 4;
    int4 ca, ra, cb, rb;
    if (va) { ca = col4[qa]; ra = row4[qa]; }
    if (vb) { cb = col4[qb]; rb = row4[qb]; }
    if (va) {
        atomicAdd(&lh[ca.x >> 11], 1); atomicAdd(&lh[ca.y >> 11], 1);
        atomicAdd(&lh[ca.z >> 11], 1); atomicAdd(&lh[ca.w >> 11], 1);
    }
    if (vb) {
        atomicAdd(&lh[cb.x >> 11], 1); atomicAdd(&lh[cb.y >> 11], 1);
        atomicAdd(&lh[cb.z >> 11], 1); atomicAdd(&lh[cb.w >> 11], 1);
    }
    __syncthreads();
    if (t < NBUCK) {
        int v = lh[t];
        if (v) lh[t] = t * BCAP + atomicAdd(&bcnt[t], v);   // reserve contiguous slice
    }
    __syncthreads();
    int p;
    if (va) {
        p = atomicAdd(&lh[ca.x >> 11], 1); part[p] = (ra.x << 11) | (ca.x & (NPB - 1));
        p = atomicAdd(&lh[ca.y >> 11], 1); part[p] = (ra.y << 11) | (ca.y & (NPB - 1));
        p = atomicAdd(&lh[ca.z >> 11], 1); part[p] = (ra.z << 11) | (ca.z & (NPB - 1));
        p = atomicAdd(&lh[ca.w >> 11], 1); part[p] = (ra.w << 11) | (ca.w & (NPB - 1));
    }
    if (vb) {
        p = atomicAdd(&lh[cb.x >> 11], 1); part[p] = (rb.x << 11) | (cb.x & (NPB - 1));
        p = atomicAdd(&lh[cb.y >> 11], 1); part[p] = (rb.y << 11) | (cb.y & (NPB - 1));
        p = atomicAdd(&lh[cb.z >> 11], 1); part[p] = (rb.z << 11) | (cb.z & (NPB - 1));
        p = atomicAdd(&lh[cb.w >> 11], 1); part[p] = (rb.w << 11) | (cb.w & (NPB - 1));
    }
}

// ---- K2: per-bucket counting sort via LDS staging (no scattered global stores)
__global__ __launch_bounds__(512) void sort2_kernel(const int* __restrict__ part,
                                                    const int* __restrict__ bcnt,
                                                    const float* __restrict__ x,
                                                    int* __restrict__ srcs,
                                                    int* __restrict__ nstart,
                                                    unsigned short* __restrict__ ndeg,
                                                    float* __restrict__ dinv,
                                                    unsigned short* __restrict__ xs) {
    __shared__ int cnt[NPB];       // 8 KB
    __shared__ int off[NPB];       // 8 KB (relative to s0)
    __shared__ int tsum[512];      // 2 KB
    __shared__ int stage[BCAP];    // 20 KB — sorted srcs staged here
    const int t = threadIdx.x, b = blockIdx.x;
    for (int i = t; i < NPB; i += 512) cnt[i] = 0;
    __syncthreads();
    const int s0 = b * BCAP, e0 = s0 + bcnt[b];
    for (int j = s0 + t; j < e0; j += 512)
        atomicAdd(&cnt[part[j] & (NPB - 1)], 1);
    __syncthreads();
    // exclusive scan of 2048 counts: 4/thread + Hillis-Steele over 512 thread sums
    const int i0 = t * 4;
    int c[4], s = 0;
#pragma unroll
    for (int q = 0; q < 4; ++q) { c[q] = cnt[i0 + q]; s += c[q]; }
    tsum[t] = s;
    __syncthreads();
    for (int o = 1; o < 512; o <<= 1) {
        int a = (t >= o) ? tsum[t - o] : 0;
        __syncthreads();
        tsum[t] += a;
        __syncthreads();
    }
    int run = tsum[t] - s;
#pragma unroll
    for (int q = 0; q < 4; ++q) { off[i0 + q] = run; run += c[q]; }
    __syncthreads();
    // per-node outputs + fused xpad (bf16, 32B rows), coalesced
    for (int i = t; i < NPB; i += 512) {
        int n = b * NPB + i;
        if (n < N_NODES) {
            int d = cnt[i];
            float dv = d ? rsqrtf((float)d) : 0.0f;
            dinv[n]   = dv;
            ndeg[n]   = (unsigned short)d;
            nstart[n] = s0 + off[i];
            const float* xr = x + (size_t)n * N_FEAT;
            unsigned h[11];
#pragma unroll
            for (int k = 0; k < 11; ++k) h[k] = f2b(dv * xr[k]);
            uint4 A, B;
            A.x = h[0] | (h[1] << 16); A.y = h[2] | (h[3] << 16);
            A.z = h[4] | (h[5] << 16); A.w = h[6] | (h[7] << 16);
            B.x = h[8] | (h[9] << 16); B.y = h[10]; B.z = 0u; B.w = 0u;
            uint4* o = (uint4*)(xs + (size_t)n * 16);
            o[0] = A; o[1] = B;
        }
    }
    __syncthreads();
    // scatter to node-sorted order — into LDS stage (relative positions)
    for (int j = s0 + t; j < e0; j += 512) {
        int p  = part[j];
        int cl = p & (NPB - 1);
        int pos = atomicAdd(&off[cl], 1);
        stage[pos] = p >> 11;
    }
    __syncthreads();
    // coalesced write-out of the staged sorted list
    const int m = e0 - s0;                 // edges in this bucket
    const int m4 = m >> 2;
    int4* d4 = (int4*)(srcs + s0);         // s0 = b*BCAP, BCAP%4==0 -> aligned
    const int4* s4 = (const int4*)stage;
    for (int j = t; j < m4; j += 512) d4[j] = s4[j];
    for (int j = (m4 << 2) + t; j < m; j += 512) srcs[s0 + j] = stage[j];
}

// ---- K3: degree-sorted register gather (bf16 xs) + transform/relu + mean-pool
__global__ __launch_bounds__(256) void gather_pool_kernel(
    const int* __restrict__ srcs, const unsigned short* __restrict__ xs,
    const int* __restrict__ nstart, const unsigned short* __restrict__ ndeg,
    const float* __restrict__ dinv, const int* __restrict__ batch,
    const float* __restrict__ Wc, const float* __restrict__ bc,
    float* __restrict__ pooled, float* __restrict__ countsf) {
    __shared__ float facc[256 * FSTR];      // 12 KB
    __shared__ int   sj0[256];
    __shared__ int   sdeg[256];
    __shared__ float sdinv[256];
    __shared__ int   sbid[256];
    __shared__ int   sperm[256];
    __shared__ int   dcnt[32];
    __shared__ int   doff[32];
    __shared__ float pbuf[NSLOT * HIDDEN];  // 2 KB
    __shared__ int   pcnt[NSLOT];
    const int t = threadIdx.x, lane = t & 63, w = t >> 6;
    const int base = blockIdx.x * 256;
    {
        int n = base + t;
        bool v = n < N_NODES;
        sj0[t]   = v ? nstart[n] : 0;
        sdeg[t]  = v ? (int)ndeg[n] : 0;
        sdinv[t] = v ? dinv[n] : 0.0f;
        sbid[t]  = v ? batch[n] : -1;
    }
    for (int i = t; i < NSLOT * HIDDEN; i += 256) pbuf[i] = 0.0f;
    if (t < NSLOT) pcnt[t] = 0;
    if (t < 32)    dcnt[t] = 0;
    __syncthreads();
    // LDS counting sort of 256 nodes by degree -> sperm
    int mybin = sdeg[t] < 31 ? sdeg[t] : 31;
    atomicAdd(&dcnt[mybin], 1);
    __syncthreads();
    if (t < 32) {
        int r = 0;
        for (int i = 0; i < t; ++i) r += dcnt[i];
        doff[t] = r;
    }
    __syncthreads();
    int pos = atomicAdd(&doff[mybin], 1);
    sperm[pos] = t;
    __syncthreads();

    // phase A: thread t aggregates node sperm[t] (wave-uniform degrees)
    {
        int i  = sperm[t];
        int j0 = sj0[i], d = sdeg[i];
        float acc[11];
#pragma unroll
        for (int k = 0; k < 11; ++k) acc[k] = 0.0f;
        for (int j = j0; j < j0 + d; ++j) {
            int r = srcs[j];
            const uint4* xr = (const uint4*)(xs + (size_t)r * 16);
            uint4 A = xr[0];
            uint2 B = *(const uint2*)(xr + 1);
            acc[0]  += __uint_as_float(A.x << 16);
            acc[1]  += __uint_as_float(A.x & 0xFFFF0000u);
            acc[2]  += __uint_as_float(A.y << 16);
            acc[3]  += __uint_as_float(A.y & 0xFFFF0000u);
            acc[4]  += __uint_as_float(A.z << 16);
            acc[5]  += __uint_as_float(A.z & 0xFFFF0000u);
            acc[6]  += __uint_as_float(A.w << 16);
            acc[7]  += __uint_as_float(A.w & 0xFFFF0000u);
            acc[8]  += __uint_as_float(B.x << 16);
            acc[9]  += __uint_as_float(B.x & 0xFFFF0000u);
            acc[10] += __uint_as_float(B.y << 16);
        }
        float* f = &facc[i * FSTR];
#pragma unroll
        for (int k = 0; k < 11; ++k) f[k] = acc[k];
    }
    __syncthreads();

    // phase B: wave w owns nodes [w*64, w*64+64); lane = hidden channel
    float wk[N_FEAT];
#pragma unroll
    for (int k = 0; k < N_FEAT; ++k) wk[k] = Wc[k * HIDDEN + lane];
    const float bias = bc[lane];
    const int bid0 = sbid[0];
    int cur = -1; float accp = 0.0f; int cntp = 0;
    for (int i = w * 64; i < w * 64 + 64; ++i) {
        int bid = sbid[i];
        if (bid < 0) break;
        if (bid != cur) {
            if (cur >= 0) {
                int slot = cur - bid0;
                if (slot >= 0 && slot < NSLOT) {
                    atomicAdd(&pbuf[slot * HIDDEN + lane], accp);
                    if (lane == 0) atomicAdd(&pcnt[slot], cntp);
                } else {
                    atomicAdd(&pooled[(size_t)cur * HIDDEN + lane], accp);
                    if (lane == 0) atomicAdd(&countsf[cur], (float)cntp);
                }
            }
            cur = bid; accp = 0.0f; cntp = 0;
        }
        float s = 0.0f;
#pragma unroll
        for (int k = 0; k < N_FEAT; ++k)
            s = fmaf(wk[k], facc[i * FSTR + k], s);   // LDS broadcast
        accp += fmaxf(fmaf(sdinv[i], s, bias), 0.0f);
        ++cntp;
    }
    if (cur >= 0) {
        int slot = cur - bid0;
        if (slot >= 0 && slot < NSLOT) {
            atomicAdd(&pbuf[slot * HIDDEN + lane], accp);
            if (lane == 0) atomicAdd(&pcnt[slot], cntp);
        } else {
            atomicAdd(&pooled[(size_t)cur * HIDDEN + lane], accp);
            if (lane == 0) atomicAdd(&countsf[cur], (float)cntp);
        }
    }
    __syncthreads();
    for (int s = w; s < NSLOT; s += 4) {
        int c = pcnt[s];
        if (c > 0) {
            atomicAdd(&pooled[(size_t)(bid0 + s) * HIDDEN + lane], pbuf[s * HIDDEN + lane]);
            if (lane == 0) atomicAdd(&countsf[bid0 + s], (float)c);
        }
    }
}

// ---- K4: out = (pooled/cnt) @ W_lin + b_lin ----
__global__ void final_kernel(const float* __restrict__ pooled, const float* __restrict__ counts,
                             const float* __restrict__ Wl, const float* __restrict__ bl,
                             float* __restrict__ out) {
    int i = blockIdx.x * blockDim.x + threadIdx.x;
    if (i >= BATCH * N_CLASSES) return;
    int b = i / N_CLASSES;
    int c = i - b * N_CLASSES;
    float inv = 1.0f / fmaxf(counts[b], 1.0f);
    float s = bl[c];
#pragma unroll 8
    for (int h = 0; h < HIDDEN; ++h)
        s = fmaf(pooled[b * HIDDEN + h] * inv, Wl[h * N_CLASSES + c], s);
    out[i] = s;
}

extern "C" void kernel_launch(void* const* d_in, const int* in_sizes, int n_in,
                              void* d_out, int out_size, void* d_ws, size_t ws_size,
                              hipStream_t stream) {
    // inputs: x, edge_index, y(unused), batch, W_conv, b_conv, W_lin, b_lin
    const float* x     = (const float*)d_in[0];
    const int*   ei    = (const int*)d_in[1];   // [2, E] int32
    const int*   batch = (const int*)d_in[3];
    const float* Wc    = (const float*)d_in[4];
    const float* bc    = (const float*)d_in[5];
    const float* Wl    = (const float*)d_in[6];
    const float* bl    = (const float*)d_in[7];
    float*       out   = (float*)d_out;

    // ws: [bcnt 512][pooled 8192][countsf 128] (zeroed, 35 KB) | xs[16M ushort] |
    //     nstart[1M] | ndeg[1M ushort] | dinv[1M] | part[489*5120] | srcs[489*5120]
    int*            bcnt    = (int*)d_ws;
    float*          pooled  = (float*)(bcnt + 512);
    float*          countsf = pooled + BATCH * HIDDEN;
    unsigned short* xs      = (unsigned short*)(countsf + BATCH);
    int*            nstart  = (int*)(xs + (size_t)N_NODES * 16);
    unsigned short* ndeg    = (unsigned short*)(nstart + N_NODES);
    float*          dinv    = (float*)(ndeg + N_NODES);
    int*            part    = (int*)(dinv + N_NODES);
    int*            srcs    = part + (size_t)NBUCK * BCAP;

    size_t zero_bytes = (512 + BATCH * HIDDEN + BATCH) * 4;
    hipMemsetAsync(d_ws, 0, zero_bytes, stream);

    const int* row = ei;
    const int* col = ei + N_EDGES;

    part_kernel <<<PBLK, 1024, 0, stream>>>(row, col, bcnt, part);
    sort2_kernel<<<NBUCK, 512, 0, stream>>>(part, bcnt, x, srcs, nstart, ndeg, dinv, xs);
    gather_pool_kernel<<<NCHUNK, 256, 0, stream>>>(srcs, xs, nstart, ndeg, dinv,
                                                   batch, Wc, bc, pooled, countsf);
    final_kernel<<<(BATCH * N_CLASSES + 255) / 256, 256, 0, stream>>>(pooled, countsf, Wl, bl, out);
}